// Round 3
// baseline (1089.643 us; speedup 1.0000x reference)
//
#include <hip/hip_runtime.h>
#include <hip/hip_bf16.h>
#include <cstdint>

#define S_LEN   4608
#define HID     2048
#define VOCAB_N 32768
#define CAPV    30.0f
#define IGNORE_IDX (-100)
#define NT512   512   // vocab partial tiles of 64 columns
#define NKT     32    // K-tiles: 2048 / 64

typedef short bf16x8 __attribute__((ext_vector_type(8)));
typedef float f32x4  __attribute__((ext_vector_type(4)));

// ---------- helpers ----------
__device__ __forceinline__ unsigned short f2bf_rtne(float f) {
    unsigned int u = __float_as_uint(f);
    unsigned int r = u + 0x7fffu + ((u >> 16) & 1u);
    return (unsigned short)(r >> 16);
}
__device__ __forceinline__ float bfr(float f) {  // fp32 -> bf16 -> fp32 (RTNE)
    unsigned int u = __float_as_uint(f);
    unsigned int r = u + 0x7fffu + ((u >> 16) & 1u);
    return __uint_as_float(r & 0xffff0000u);
}
__device__ __forceinline__ float bf_lo(unsigned int u) { return __uint_as_float(u << 16); }
__device__ __forceinline__ float bf_hi(unsigned int u) { return __uint_as_float(u & 0xffff0000u); }
__device__ __forceinline__ float bfdot2(unsigned int x, unsigned int w) {
    return bf_lo(x) * bf_lo(w) + bf_hi(x) * bf_hi(w);
}
// Reference-matched softcap: logit, logit/CAP and tanh rounded through bf16.
__device__ __forceinline__ float softcap_ref(float logit) {
    float lb = bfr(logit);
    float x  = bfr(lb / CAPV);
    float e  = __expf(2.0f * x);
    float t  = bfr((e - 1.0f) / (e + 1.0f));
    return CAPV * t;
}

// ---------- kernel 0: fp32 -> bf16 convert of hidden (+ zero the output scalar) ----------
__global__ void cvt_kernel(const float* __restrict__ h, unsigned short* __restrict__ xb,
                           float* __restrict__ out) {
    if (blockIdx.x == 0 && threadIdx.x == 0) out[0] = 0.0f;
    int i = blockIdx.x * blockDim.x + threadIdx.x;   // one float4 per thread, exact cover
    float4 v = ((const float4*)h)[i];
    ushort4 o;
    o.x = f2bf_rtne(v.x); o.y = f2bf_rtne(v.y);
    o.z = f2bf_rtne(v.z); o.w = f2bf_rtne(v.w);
    ((ushort4*)xb)[i] = o;
}

// ---------- kernel 1: 256x256 / 8-wave / BK=64 8-phase GEMM + softcap + partial sum-exp ----
// R3 change vs R2: staging moved ONE FULL TILE ahead of consumption and waits collapsed
// to ONE counted vmcnt per K-tile.  R2 staged B(t+1) at P0/P1 of tile t and read it at
// P3 of tile t (2-phase slack ~300cy << L3/HBM latency 600-900cy) -> all 8 lockstep
// waves parked at vmcnt(2)/vmcnt(4) every tile (MfmaUtil stuck ~34%).
// New uniform tile body (tile u, CUR=parity(u)):
//   P0: rd bv23(CUR)                                   | MFMA(0,0)
//   P1: rd av47(CUR); stage B(u+2)h0+h1 -> Bs[CUR]     | MFMA(0,1); vmcnt(4)
//   P2: rd av03(NXT); stage A(u+2)h0+h1 -> As[CUR]     | MFMA(1,0)
//   P3: rd bv01(NXT)                                   | MFMA(1,1)
// In-flight induction at the end-P1 vmcnt(4): outstanding = {B(u+1)x4 (P1 of u-1),
// A(u+1)x4 (P2 of u-1), B(u+2)x4 (P1 of u)} = 12 loads; vmcnt(4) lands exactly
// A(u+1) (needed P2) + B(u+1) (needed P3), keeps B(u+2) in flight.  B slack = 6
// phases, A slack = 4 phases; never drains to 0 in the main loop.
// Region safety: Bs[CUR] last read at P0 (RD_B(CUR,1)), staged at P1 (barrier between);
// As[CUR] last read at P1, staged at P2 -- same window as the verified m201 template.
__global__ __launch_bounds__(512, 2)
void gemm_lse_kernel(const unsigned short* __restrict__ X,
                     const unsigned short* __restrict__ W,
                     float* __restrict__ partL) {
    __shared__ __align__(16) unsigned short As[2][256 * 64];
    __shared__ __align__(16) unsigned short Bs[2][256 * 64];

    const int tid  = threadIdx.x;
    const int wid  = tid >> 6;
    const int lane = tid & 63;
    const int wr   = wid >> 2;            // 0..1 : M half of the wave grid
    const int wc   = wid & 3;             // 0..3 : N quarter
    const int q    = lane >> 4, l16 = lane & 15;
    const int tileM = blockIdx.x * 256;
    const int tileN = blockIdx.y * 256;

    // staging per-thread map: 512 threads x 16B = 64 rows x 8 chunks per load.
    const int srow = lane >> 3;                 // 0..7 (row within the wave's 8)
    const int csrc = (lane & 7) ^ srow;         // pre-swizzled global source chunk
    const unsigned short* Ag = X + (size_t)(tileM + wid * 8 + srow) * HID + csrc * 8;
    const unsigned short* Wg = W + (size_t)(tileN + wid * 8 + srow) * HID + csrc * 8;

    // fragment-read constants: row = .. + l16, chunk c=kk*4+q lives at slot c^(l16&7)
    const int abase = (wr * 128 + l16) * 64;
    const int bbase = (wc * 64  + l16) * 64;
    const int koff0 = ((q    ) ^ (l16 & 7)) * 8;
    const int koff1 = ((q + 4) ^ (l16 & 7)) * 8;

    bf16x8 av[8][2], bv[4][2];
    f32x4  acc[8][4] = {};

#define STAGE_A(BUF, H, KT) do {                                                          \
    const unsigned short* _g = Ag + (size_t)(H) * 128 * HID + (size_t)(KT) * 64;          \
    __builtin_amdgcn_global_load_lds(                                                     \
        (const __attribute__((address_space(1))) void*)_g,                                \
        (__attribute__((address_space(3))) void*)&As[BUF][((H) * 128 + wid * 8) * 64],    \
        16, 0, 0);                                                                        \
    __builtin_amdgcn_global_load_lds(                                                     \
        (const __attribute__((address_space(1))) void*)(_g + (size_t)64 * HID),           \
        (__attribute__((address_space(3))) void*)&As[BUF][((H) * 128 + 64 + wid * 8) * 64],\
        16, 0, 0);                                                                        \
} while (0)

#define STAGE_B(BUF, H, KT) do {                                                          \
    const unsigned short* _g = Wg + (size_t)(H) * 128 * HID + (size_t)(KT) * 64;          \
    __builtin_amdgcn_global_load_lds(                                                     \
        (const __attribute__((address_space(1))) void*)_g,                                \
        (__attribute__((address_space(3))) void*)&Bs[BUF][((H) * 128 + wid * 8) * 64],    \
        16, 0, 0);                                                                        \
    __builtin_amdgcn_global_load_lds(                                                     \
        (const __attribute__((address_space(1))) void*)(_g + (size_t)64 * HID),           \
        (__attribute__((address_space(3))) void*)&Bs[BUF][((H) * 128 + 64 + wid * 8) * 64],\
        16, 0, 0);                                                                        \
} while (0)

// RD_A(BUF, MH): av[MH*4 .. MH*4+3][0..1]  (8x ds_read_b128)
#define RD_A(BUF, MH) do {                                                                \
    _Pragma("unroll") for (int fm = 0; fm < 4; ++fm) {                                    \
        av[(MH) * 4 + fm][0] = *(const bf16x8*)&As[BUF][abase + ((MH) * 64 + fm * 16) * 64 + koff0]; \
        av[(MH) * 4 + fm][1] = *(const bf16x8*)&As[BUF][abase + ((MH) * 64 + fm * 16) * 64 + koff1]; \
    } } while (0)

// RD_B(BUF, NH): bv[NH*2 .. NH*2+1][0..1]  (4x ds_read_b128)
#define RD_B(BUF, NH) do {                                                                \
    _Pragma("unroll") for (int fn = 0; fn < 2; ++fn) {                                    \
        bv[(NH) * 2 + fn][0] = *(const bf16x8*)&Bs[BUF][bbase + ((NH) * 32 + fn * 16) * 64 + koff0]; \
        bv[(NH) * 2 + fn][1] = *(const bf16x8*)&Bs[BUF][bbase + ((NH) * 32 + fn * 16) * 64 + koff1]; \
    } } while (0)

#define MFMAQ(MH, NH) do {                                                                \
    _Pragma("unroll") for (int kk = 0; kk < 2; ++kk)                                      \
    _Pragma("unroll") for (int fm = 0; fm < 4; ++fm)                                      \
    _Pragma("unroll") for (int fn = 0; fn < 2; ++fn)                                      \
        acc[(MH) * 4 + fm][(NH) * 2 + fn] = __builtin_amdgcn_mfma_f32_16x16x32_bf16(      \
            av[(MH) * 4 + fm][kk], bv[(NH) * 2 + fn][kk],                                 \
            acc[(MH) * 4 + fm][(NH) * 2 + fn], 0, 0, 0);                                  \
} while (0)

#define BAR()   __builtin_amdgcn_s_barrier()
#define PRIO1() __builtin_amdgcn_s_setprio(1)
#define PRIO0() __builtin_amdgcn_s_setprio(0)
#define VMCNT8() asm volatile("s_waitcnt vmcnt(8)" ::: "memory")
#define VMCNT4() asm volatile("s_waitcnt vmcnt(4)" ::: "memory")
#define VMCNT0() asm volatile("s_waitcnt vmcnt(0)" ::: "memory")

#define KTILE(CUR, NXT, T) do {                                                           \
    RD_B(CUR, 1);                                                                         \
    BAR(); PRIO1(); MFMAQ(0, 0); PRIO0(); BAR();                                          \
    RD_A(CUR, 1); STAGE_B(CUR, 0, (T) + 2); STAGE_B(CUR, 1, (T) + 2);                     \
    BAR(); PRIO1(); MFMAQ(0, 1); PRIO0(); VMCNT4(); BAR();                                \
    RD_A(NXT, 0); STAGE_A(CUR, 0, (T) + 2); STAGE_A(CUR, 1, (T) + 2);                     \
    BAR(); PRIO1(); MFMAQ(1, 0); PRIO0(); BAR();                                          \
    RD_B(NXT, 0);                                                                         \
    BAR(); PRIO1(); MFMAQ(1, 1); PRIO0(); BAR();                                          \
} while (0)

    // ---- prologue: tile0 (B then A) -> buf0, tile1 (B then A) -> buf1 ----
    // FIFO order matters for the counted waits: B0,A0 are the oldest 8 loads.
    STAGE_B(0, 0, 0); STAGE_B(0, 1, 0);
    STAGE_A(0, 0, 0); STAGE_A(0, 1, 0);
    STAGE_B(1, 0, 1); STAGE_B(1, 1, 1);
    STAGE_A(1, 0, 1); STAGE_A(1, 1, 1);
    VMCNT8();          // tile0 landed; tile1's 8 loads in flight
    BAR();
    RD_A(0, 0); RD_B(0, 0);   // fragments for tile0 P0

    // ---- main loop: tiles 0..29 full body (last stages target tile 31) ----
    #pragma unroll 1
    for (int t = 0; t < NKT - 2; t += 2) {
        KTILE(0, 1, t);
        KTILE(1, 0, t + 1);
    }

    // ---- tile 30 (CUR=0): no stages; drain A(31),B(31) at the P1 wait ----
    RD_B(0, 1);
    BAR(); PRIO1(); MFMAQ(0, 0); PRIO0(); BAR();
    RD_A(0, 1);
    BAR(); PRIO1(); MFMAQ(0, 1); PRIO0(); VMCNT0(); BAR();
    RD_A(1, 0);
    BAR(); PRIO1(); MFMAQ(1, 0); PRIO0(); BAR();
    RD_B(1, 0);
    BAR(); PRIO1(); MFMAQ(1, 1); PRIO0(); BAR();

    // ---- tile 31 (CUR=1): everything landed, no writers -> no barriers ----
    RD_B(1, 1);
    PRIO1(); MFMAQ(0, 0); PRIO0();
    RD_A(1, 1);
    PRIO1(); MFMAQ(0, 1); PRIO0();
    PRIO1(); MFMAQ(1, 0); PRIO0();
    PRIO1(); MFMAQ(1, 1); PRIO0();

    // ---- epilogue: softcap + exp + 64-col partial sums ----
    // C layout per 16x16: col = l16 (vocab), row = q*4 + reg (seq).
    // Wave covers exactly one 64-col partL tile: ntile = blockIdx.y*4 + wc.
    const int rowbase = tileM + wr * 128;
    const int ntile   = blockIdx.y * 4 + wc;
    #pragma unroll
    for (int m = 0; m < 8; ++m) {
        #pragma unroll
        for (int r = 0; r < 4; ++r) {
            float s = 0.0f;
            #pragma unroll
            for (int n = 0; n < 4; ++n)
                s += __expf(softcap_ref(acc[m][n][r]));
            s += __shfl_xor(s, 1);
            s += __shfl_xor(s, 2);
            s += __shfl_xor(s, 4);
            s += __shfl_xor(s, 8);
            if (l16 == 0)
                partL[(size_t)(rowbase + m * 16 + q * 4 + r) * NT512 + ntile] = s;
        }
    }

#undef STAGE_A
#undef STAGE_B
#undef RD_A
#undef RD_B
#undef MFMAQ
#undef BAR
#undef PRIO1
#undef PRIO0
#undef VMCNT8
#undef VMCNT4
#undef VMCNT0
#undef KTILE
}

// ---------- kernel 2: per-row label logit + logsumexp reduce -> atomic total ----------
__global__ void row_reduce_kernel(const unsigned short* __restrict__ X,
                                  const unsigned short* __restrict__ W,
                                  const int* __restrict__ ids,
                                  const int* __restrict__ am,
                                  const float* __restrict__ partL,
                                  float* __restrict__ out) {
    __shared__ float blk[4];
    const int wave = threadIdx.x >> 6;
    const int lane = threadIdx.x & 63;
    const int r = blockIdx.x * 4 + wave;

    int lab = IGNORE_IDX;
    if (r < S_LEN - 1 && am[r + 1] != 0) lab = ids[r + 1];
    const bool valid = (lab >= 0 && lab < VOCAB_N);

    float dot = 0.0f;
    if (valid) {
        const unsigned short* xr = X + (size_t)r   * HID;
        const unsigned short* wr = W + (size_t)lab * HID;
        #pragma unroll
        for (int c = 0; c < 4; ++c) {
            const int off = c * 512 + lane * 8;
            uint4 xu = *(const uint4*)(xr + off);
            uint4 wu = *(const uint4*)(wr + off);
            dot += bfdot2(xu.x, wu.x) + bfdot2(xu.y, wu.y) +
                   bfdot2(xu.z, wu.z) + bfdot2(xu.w, wu.w);
        }
    }
    #pragma unroll
    for (int m = 1; m < 64; m <<= 1) dot += __shfl_xor(dot, m);

    float L = 0.0f;
    const float* pr = partL + (size_t)r * NT512;
    #pragma unroll
    for (int i = 0; i < 8; ++i) L += pr[i * 64 + lane];
    #pragma unroll
    for (int m = 1; m < 64; m <<= 1) L += __shfl_xor(L, m);

    if (lane == 0) {
        float loss = 0.0f;
        if (valid) loss = logf(L) - softcap_ref(dot);
        blk[wave] = loss;
    }
    __syncthreads();
    if (threadIdx.x == 0)
        atomicAdd(out, blk[0] + blk[1] + blk[2] + blk[3]);
}

extern "C" void kernel_launch(void* const* d_in, const int* in_sizes, int n_in,
                              void* d_out, int out_size, void* d_ws, size_t ws_size,
                              hipStream_t stream) {
    const unsigned short* W  = (const unsigned short*)d_in[0];  // bf16 [V, H]
    const float*  hidden     = (const float*)d_in[1];           // fp32 [1, S, H]
    const int*    ids        = (const int*)d_in[2];             // [1, S]
    const int*    am         = (const int*)d_in[3];             // [1, S]
    float* out = (float*)d_out;

    char* ws = (char*)d_ws;
    unsigned short* Xb = (unsigned short*)ws;                          // S*H bf16
    float* partL       = (float*)(ws + (size_t)S_LEN * HID * 2);       // S*512 f32

    cvt_kernel<<<(S_LEN * HID / 4) / 256, 256, 0, stream>>>(hidden, Xb, out);

    dim3 g(S_LEN / 256, VOCAB_N / 256);    // x = M (18), y = N (128): W reuse across x
    gemm_lse_kernel<<<g, 512, 0, stream>>>(Xb, W, partL);

    row_reduce_kernel<<<S_LEN / 4, 256, 0, stream>>>(Xb, W, ids, am, partL, out);
}

// Round 4
// 1050.559 us; speedup vs baseline: 1.0372x; 1.0372x over previous
//
#include <hip/hip_runtime.h>
#include <hip/hip_bf16.h>
#include <cstdint>

#define S_LEN   4608
#define HID     2048
#define VOCAB_N 32768
#define CAPV    30.0f
#define IGNORE_IDX (-100)
#define NT512   512   // vocab partial tiles of 64 columns
#define NKT     32    // K-tiles: 2048 / 64

typedef short bf16x8 __attribute__((ext_vector_type(8)));
typedef float f32x4  __attribute__((ext_vector_type(4)));

// ---------- helpers ----------
__device__ __forceinline__ unsigned short f2bf_rtne(float f) {
    unsigned int u = __float_as_uint(f);
    unsigned int r = u + 0x7fffu + ((u >> 16) & 1u);
    return (unsigned short)(r >> 16);
}
__device__ __forceinline__ float bfr(float f) {  // fp32 -> bf16 -> fp32 (RTNE)
    unsigned int u = __float_as_uint(f);
    unsigned int r = u + 0x7fffu + ((u >> 16) & 1u);
    return __uint_as_float(r & 0xffff0000u);
}
__device__ __forceinline__ float bf_lo(unsigned int u) { return __uint_as_float(u << 16); }
__device__ __forceinline__ float bf_hi(unsigned int u) { return __uint_as_float(u & 0xffff0000u); }
__device__ __forceinline__ float bfdot2(unsigned int x, unsigned int w) {
    return bf_lo(x) * bf_lo(w) + bf_hi(x) * bf_hi(w);
}
// Reference-matched softcap: logit, logit/CAP and tanh rounded through bf16.
__device__ __forceinline__ float softcap_ref(float logit) {
    float lb = bfr(logit);
    float x  = bfr(lb / CAPV);
    float e  = __expf(2.0f * x);
    float t  = bfr((e - 1.0f) / (e + 1.0f));
    return CAPV * t;
}

// ---------- kernel 0: fp32 -> bf16 convert of hidden (+ zero the output scalar) ----------
__global__ void cvt_kernel(const float* __restrict__ h, unsigned short* __restrict__ xb,
                           float* __restrict__ out) {
    if (blockIdx.x == 0 && threadIdx.x == 0) out[0] = 0.0f;
    int i = blockIdx.x * blockDim.x + threadIdx.x;   // one float4 per thread, exact cover
    float4 v = ((const float4*)h)[i];
    ushort4 o;
    o.x = f2bf_rtne(v.x); o.y = f2bf_rtne(v.y);
    o.z = f2bf_rtne(v.z); o.w = f2bf_rtne(v.w);
    ((ushort4*)xb)[i] = o;
}

// ---------- kernel 1: 256x256 / 8-wave / BK=64 8-phase GEMM + softcap + partial sum-exp ----
// R4 change vs R2/R3: XCD-affinity block remap.  Evidence: dur ~= hbm_bytes / 1.5TB/s
// across R0/R2/R3 (schedule-invariant), FETCH ~= 8.8x W -> W was fetched once per XCD
// because the 18 sharers of each W-panel were round-robined across all 8 XCDs (L2-level
// reuse only; L3 does not absorb the duplication).  Remap (dispatch round-robins
// consecutive blockIdx across XCDs, 2304 % 8 == 0 -> bijective):
//   xcd = bid & 7, slot = bid >> 3, xt = slot % 18, yt = (slot/18)*8 + xcd
// All 18 sharers of W-panel yt become consecutive slots ON THE SAME XCD (co-resident,
// 18 < 32 CUs/XCD); the 1 MB panel fits the 4 MB L2 -> one HBM fetch per panel.
// Schedule = R2's verbatim (best 8-phase):
//   P0: rd bv23(CUR); stage B(t+1)h0 | MFMA(0,0)
//   P1: rd av47(CUR); stage B(t+1)h1 | MFMA(0,1); vmcnt(4)
//   P2: rd av03(NXT); stage A(t+2)h0 | MFMA(1,0); vmcnt(2)
//   P3: rd bv01(NXT); stage A(t+2)h1 | MFMA(1,1)
__global__ __launch_bounds__(512, 2)
void gemm_lse_kernel(const unsigned short* __restrict__ X,
                     const unsigned short* __restrict__ W,
                     float* __restrict__ partL) {
    __shared__ __align__(16) unsigned short As[2][256 * 64];
    __shared__ __align__(16) unsigned short Bs[2][256 * 64];

    const int tid  = threadIdx.x;
    const int wid  = tid >> 6;
    const int lane = tid & 63;
    const int wr   = wid >> 2;            // 0..1 : M half of the wave grid
    const int wc   = wid & 3;             // 0..3 : N quarter
    const int q    = lane >> 4, l16 = lane & 15;

    // XCD-affinity remap: pin each W-panel (yt) to one XCD; its 18 M-sharers are
    // consecutive dispatch slots there -> panel read from HBM once, 17 L2 hits.
    const int bid  = blockIdx.x;
    const int xcd  = bid & 7;
    const int slot = bid >> 3;            // 0..287
    const int xt   = slot % 18;           // M-tile
    const int yt   = (slot / 18) * 8 + xcd;  // N-tile, pinned to this XCD
    const int tileM = xt * 256;
    const int tileN = yt * 256;

    // staging per-thread map: 512 threads x 16B = 64 rows x 8 chunks per load.
    const int srow = lane >> 3;                 // 0..7 (row within the wave's 8)
    const int csrc = (lane & 7) ^ srow;         // pre-swizzled global source chunk
    const unsigned short* Ag = X + (size_t)(tileM + wid * 8 + srow) * HID + csrc * 8;
    const unsigned short* Wg = W + (size_t)(tileN + wid * 8 + srow) * HID + csrc * 8;

    // fragment-read constants: row = .. + l16, chunk c=kk*4+q lives at slot c^(l16&7)
    const int abase = (wr * 128 + l16) * 64;
    const int bbase = (wc * 64  + l16) * 64;
    const int koff0 = ((q    ) ^ (l16 & 7)) * 8;
    const int koff1 = ((q + 4) ^ (l16 & 7)) * 8;

    bf16x8 av[8][2], bv[4][2];
    f32x4  acc[8][4] = {};

#define STAGE_A(BUF, H, KT) do {                                                          \
    const unsigned short* _g = Ag + (size_t)(H) * 128 * HID + (size_t)(KT) * 64;          \
    __builtin_amdgcn_global_load_lds(                                                     \
        (const __attribute__((address_space(1))) void*)_g,                                \
        (__attribute__((address_space(3))) void*)&As[BUF][((H) * 128 + wid * 8) * 64],    \
        16, 0, 0);                                                                        \
    __builtin_amdgcn_global_load_lds(                                                     \
        (const __attribute__((address_space(1))) void*)(_g + (size_t)64 * HID),           \
        (__attribute__((address_space(3))) void*)&As[BUF][((H) * 128 + 64 + wid * 8) * 64],\
        16, 0, 0);                                                                        \
} while (0)

#define STAGE_B(BUF, H, KT) do {                                                          \
    const unsigned short* _g = Wg + (size_t)(H) * 128 * HID + (size_t)(KT) * 64;          \
    __builtin_amdgcn_global_load_lds(                                                     \
        (const __attribute__((address_space(1))) void*)_g,                                \
        (__attribute__((address_space(3))) void*)&Bs[BUF][((H) * 128 + wid * 8) * 64],    \
        16, 0, 0);                                                                        \
    __builtin_amdgcn_global_load_lds(                                                     \
        (const __attribute__((address_space(1))) void*)(_g + (size_t)64 * HID),           \
        (__attribute__((address_space(3))) void*)&Bs[BUF][((H) * 128 + 64 + wid * 8) * 64],\
        16, 0, 0);                                                                        \
} while (0)

// RD_A(BUF, MH): av[MH*4 .. MH*4+3][0..1]  (8x ds_read_b128)
#define RD_A(BUF, MH) do {                                                                \
    _Pragma("unroll") for (int fm = 0; fm < 4; ++fm) {                                    \
        av[(MH) * 4 + fm][0] = *(const bf16x8*)&As[BUF][abase + ((MH) * 64 + fm * 16) * 64 + koff0]; \
        av[(MH) * 4 + fm][1] = *(const bf16x8*)&As[BUF][abase + ((MH) * 64 + fm * 16) * 64 + koff1]; \
    } } while (0)

// RD_B(BUF, NH): bv[NH*2 .. NH*2+1][0..1]  (4x ds_read_b128)
#define RD_B(BUF, NH) do {                                                                \
    _Pragma("unroll") for (int fn = 0; fn < 2; ++fn) {                                    \
        bv[(NH) * 2 + fn][0] = *(const bf16x8*)&Bs[BUF][bbase + ((NH) * 32 + fn * 16) * 64 + koff0]; \
        bv[(NH) * 2 + fn][1] = *(const bf16x8*)&Bs[BUF][bbase + ((NH) * 32 + fn * 16) * 64 + koff1]; \
    } } while (0)

#define MFMAQ(MH, NH) do {                                                                \
    _Pragma("unroll") for (int kk = 0; kk < 2; ++kk)                                      \
    _Pragma("unroll") for (int fm = 0; fm < 4; ++fm)                                      \
    _Pragma("unroll") for (int fn = 0; fn < 2; ++fn)                                      \
        acc[(MH) * 4 + fm][(NH) * 2 + fn] = __builtin_amdgcn_mfma_f32_16x16x32_bf16(      \
            av[(MH) * 4 + fm][kk], bv[(NH) * 2 + fn][kk],                                 \
            acc[(MH) * 4 + fm][(NH) * 2 + fn], 0, 0, 0);                                  \
} while (0)

#define BAR()   __builtin_amdgcn_s_barrier()
#define PRIO1() __builtin_amdgcn_s_setprio(1)
#define PRIO0() __builtin_amdgcn_s_setprio(0)
#define VMCNT4() asm volatile("s_waitcnt vmcnt(4)" ::: "memory")
#define VMCNT2() asm volatile("s_waitcnt vmcnt(2)" ::: "memory")
#define VMCNT0() asm volatile("s_waitcnt vmcnt(0)" ::: "memory")

#define KTILE(CUR, NXT, T) do {                                                           \
    RD_B(CUR, 1); STAGE_B(NXT, 0, (T) + 1);                                               \
    BAR(); PRIO1(); MFMAQ(0, 0); PRIO0(); BAR();                                          \
    RD_A(CUR, 1); STAGE_B(NXT, 1, (T) + 1);                                               \
    BAR(); PRIO1(); MFMAQ(0, 1); PRIO0(); VMCNT4(); BAR();                                \
    RD_A(NXT, 0); STAGE_A(CUR, 0, (T) + 2);                                               \
    BAR(); PRIO1(); MFMAQ(1, 0); PRIO0(); VMCNT2(); BAR();                                \
    RD_B(NXT, 0); STAGE_A(CUR, 1, (T) + 2);                                               \
    BAR(); PRIO1(); MFMAQ(1, 1); PRIO0(); BAR();                                          \
} while (0)

    // ---- prologue: K-tile0 (4 halves) -> buf0, K-tile1 A halves -> buf1 ----
    STAGE_A(0, 0, 0); STAGE_A(0, 1, 0);
    STAGE_B(0, 0, 0); STAGE_B(0, 1, 0);
    STAGE_A(1, 0, 1); STAGE_A(1, 1, 1);
    VMCNT4();          // K-tile0's 8 loads landed; K-tile1's A halves in flight
    BAR();
    RD_A(0, 0); RD_B(0, 0);   // fragments for tile0 P0

    // ---- main loop: K-tiles 0..29, 2 per iteration (static buffer indices) ----
    #pragma unroll 1
    for (int t = 0; t < NKT - 2; t += 2) {
        KTILE(0, 1, t);
        KTILE(1, 0, t + 1);
    }

    // ---- t = 30 (cur=0): stage only B(31); read tile-31 fragments ----
    RD_B(0, 1); STAGE_B(1, 0, 31);
    BAR(); PRIO1(); MFMAQ(0, 0); PRIO0(); BAR();
    RD_A(0, 1); STAGE_B(1, 1, 31);
    BAR(); PRIO1(); MFMAQ(0, 1); PRIO0(); VMCNT4(); BAR();   // A(31) landed
    RD_A(1, 0);
    BAR(); PRIO1(); MFMAQ(1, 0); PRIO0(); VMCNT0(); BAR();   // B(31) landed
    RD_B(1, 0);
    BAR(); PRIO1(); MFMAQ(1, 1); PRIO0(); BAR();

    // ---- t = 31 (cur=1): no stages, no barriers needed ----
    RD_B(1, 1);
    PRIO1(); MFMAQ(0, 0); PRIO0();
    RD_A(1, 1);
    PRIO1(); MFMAQ(0, 1); PRIO0();
    PRIO1(); MFMAQ(1, 0); PRIO0();
    PRIO1(); MFMAQ(1, 1); PRIO0();

    // ---- epilogue: softcap + exp + 64-col partial sums ----
    // C layout per 16x16: col = l16 (vocab), row = q*4 + reg (seq).
    // Wave covers exactly one 64-col partL tile: ntile = yt*4 + wc.
    const int rowbase = tileM + wr * 128;
    const int ntile   = yt * 4 + wc;
    #pragma unroll
    for (int m = 0; m < 8; ++m) {
        #pragma unroll
        for (int r = 0; r < 4; ++r) {
            float s = 0.0f;
            #pragma unroll
            for (int n = 0; n < 4; ++n)
                s += __expf(softcap_ref(acc[m][n][r]));
            s += __shfl_xor(s, 1);
            s += __shfl_xor(s, 2);
            s += __shfl_xor(s, 4);
            s += __shfl_xor(s, 8);
            if (l16 == 0)
                partL[(size_t)(rowbase + m * 16 + q * 4 + r) * NT512 + ntile] = s;
        }
    }

#undef STAGE_A
#undef STAGE_B
#undef RD_A
#undef RD_B
#undef MFMAQ
#undef BAR
#undef PRIO1
#undef PRIO0
#undef VMCNT4
#undef VMCNT2
#undef VMCNT0
#undef KTILE
}

// ---------- kernel 2: per-row label logit + logsumexp reduce -> atomic total ----------
__global__ void row_reduce_kernel(const unsigned short* __restrict__ X,
                                  const unsigned short* __restrict__ W,
                                  const int* __restrict__ ids,
                                  const int* __restrict__ am,
                                  const float* __restrict__ partL,
                                  float* __restrict__ out) {
    __shared__ float blk[4];
    const int wave = threadIdx.x >> 6;
    const int lane = threadIdx.x & 63;
    const int r = blockIdx.x * 4 + wave;

    int lab = IGNORE_IDX;
    if (r < S_LEN - 1 && am[r + 1] != 0) lab = ids[r + 1];
    const bool valid = (lab >= 0 && lab < VOCAB_N);

    float dot = 0.0f;
    if (valid) {
        const unsigned short* xr = X + (size_t)r   * HID;
        const unsigned short* wr = W + (size_t)lab * HID;
        #pragma unroll
        for (int c = 0; c < 4; ++c) {
            const int off = c * 512 + lane * 8;
            uint4 xu = *(const uint4*)(xr + off);
            uint4 wu = *(const uint4*)(wr + off);
            dot += bfdot2(xu.x, wu.x) + bfdot2(xu.y, wu.y) +
                   bfdot2(xu.z, wu.z) + bfdot2(xu.w, wu.w);
        }
    }
    #pragma unroll
    for (int m = 1; m < 64; m <<= 1) dot += __shfl_xor(dot, m);

    float L = 0.0f;
    const float* pr = partL + (size_t)r * NT512;
    #pragma unroll
    for (int i = 0; i < 8; ++i) L += pr[i * 64 + lane];
    #pragma unroll
    for (int m = 1; m < 64; m <<= 1) L += __shfl_xor(L, m);

    if (lane == 0) {
        float loss = 0.0f;
        if (valid) loss = logf(L) - softcap_ref(dot);
        blk[wave] = loss;
    }
    __syncthreads();
    if (threadIdx.x == 0)
        atomicAdd(out, blk[0] + blk[1] + blk[2] + blk[3]);
}

extern "C" void kernel_launch(void* const* d_in, const int* in_sizes, int n_in,
                              void* d_out, int out_size, void* d_ws, size_t ws_size,
                              hipStream_t stream) {
    const unsigned short* W  = (const unsigned short*)d_in[0];  // bf16 [V, H]
    const float*  hidden     = (const float*)d_in[1];           // fp32 [1, S, H]
    const int*    ids        = (const int*)d_in[2];             // [1, S]
    const int*    am         = (const int*)d_in[3];             // [1, S]
    float* out = (float*)d_out;

    char* ws = (char*)d_ws;
    unsigned short* Xb = (unsigned short*)ws;                          // S*H bf16
    float* partL       = (float*)(ws + (size_t)S_LEN * HID * 2);       // S*512 f32

    cvt_kernel<<<(S_LEN * HID / 4) / 256, 256, 0, stream>>>(hidden, Xb, out);

    // 1D grid, XCD-affinity remap inside the kernel (2304 blocks, 2304 % 8 == 0)
    gemm_lse_kernel<<<(S_LEN / 256) * (VOCAB_N / 256), 512, 0, stream>>>(Xb, W, partL);

    row_reduce_kernel<<<S_LEN / 4, 256, 0, stream>>>(Xb, W, ids, am, partL, out);
}